// Round 14
// baseline (154.331 us; speedup 1.0000x reference)
//
#include <hip/hip_runtime.h>

// Problem constants (B=4, N=512, D_in=512, D_out=256), fp32 in/out.
constexpr int Bq   = 4;
constexpr int Nq   = 512;
constexpr int DIN  = 512;
constexpr int DOUT = 256;

typedef _Float16 h2  __attribute__((ext_vector_type(2)));
typedef _Float16 h4  __attribute__((ext_vector_type(4)));
typedef _Float16 h8  __attribute__((ext_vector_type(8)));
typedef float    f4v __attribute__((ext_vector_type(4)));

#if defined(__has_builtin) && __has_builtin(__builtin_amdgcn_fdot2)
__device__ __forceinline__ float fdot2f(h2 a, h2 b, float c) {
    return __builtin_amdgcn_fdot2(a, b, c, false);   // v_dot2_f32_f16
}
#else
__device__ __forceinline__ float fdot2f(h2 a, h2 b, float c) {
    return (float)a.x * (float)b.x + (float)a.y * (float)b.y + c;
}
#endif

// ---------------------------------------------------------------------------
// K1: Wh = H @ W^T via MFMA 16x16x32 f16, converting fp32->fp16 inline.
// Grid 512 x 256 thr. Wave = one 16x16 tile (same verified mapping as R13:
// A[m=lane&15][k=quad*8+j], C col=lane&15 row=quad*4+reg).
// Epilogue emits 3 fp16 layouts (no fp32 Wh):
//   Wh16[n][o2]          (phase-A uniform rows)
//   WhT16p[b][o2][j]     (phase-A j-stream, o-pairs)  [pack via shfl_xor 1]
//   WhTj16[b][o][j2]     (phase-B j-pair stream)      [pack from adjacent regs]
// Block 0 also converts a -> a16. No LDS, no barriers.
// ---------------------------------------------------------------------------
__global__ __launch_bounds__(256) void k1_wh(const float* __restrict__ H,
                                             const float* __restrict__ W,
                                             const float* __restrict__ a,
                                             h2* __restrict__ Wh16,
                                             h2* __restrict__ WhT16p,
                                             h2* __restrict__ WhTj16,
                                             h2* __restrict__ a16) {
    const int t    = threadIdx.x;
    const int w    = t >> 6;
    const int lane = t & 63;
    const int bid  = blockIdx.x;          // 512
    const int mt   = bid >> 2;            // 0..127
    const int b    = mt & 3;              // XCD spread
    const int n0   = (mt >> 2) << 4;      // 0..496
    const int o0   = ((bid & 3) << 6) + (w << 4);
    const int quad = lane >> 4;
    const int col  = lane & 15;

    if (bid == 0 && t < 128) {            // a -> fp16 (read by k23 only)
        const float2 v = *(const float2*)&a[2 * t];
        h2 hv; hv.x = (_Float16)v.x; hv.y = (_Float16)v.y;
        a16[t] = hv;
    }

    const float* __restrict__ aPtr = H + (size_t)(b * Nq + n0 + col) * DIN + quad * 8;
    const float* __restrict__ bPtr = W + (size_t)(o0 + col) * DIN + quad * 8;

    f4v acc = {0.f, 0.f, 0.f, 0.f};
    float4 af0 = *(const float4*)aPtr;
    float4 af1 = *(const float4*)(aPtr + 4);
    float4 bf0 = *(const float4*)bPtr;
    float4 bf1 = *(const float4*)(bPtr + 4);

#pragma unroll
    for (int kb = 0; kb < 16; ++kb) {
        h8 av, bv;
        av[0] = (_Float16)af0.x; av[1] = (_Float16)af0.y;
        av[2] = (_Float16)af0.z; av[3] = (_Float16)af0.w;
        av[4] = (_Float16)af1.x; av[5] = (_Float16)af1.y;
        av[6] = (_Float16)af1.z; av[7] = (_Float16)af1.w;
        bv[0] = (_Float16)bf0.x; bv[1] = (_Float16)bf0.y;
        bv[2] = (_Float16)bf0.z; bv[3] = (_Float16)bf0.w;
        bv[4] = (_Float16)bf1.x; bv[5] = (_Float16)bf1.y;
        bv[6] = (_Float16)bf1.z; bv[7] = (_Float16)bf1.w;
        if (kb < 15) {                    // prefetch next 32-k block
            af0 = *(const float4*)(aPtr + (kb + 1) * 32);
            af1 = *(const float4*)(aPtr + (kb + 1) * 32 + 4);
            bf0 = *(const float4*)(bPtr + (kb + 1) * 32);
            bf1 = *(const float4*)(bPtr + (kb + 1) * 32 + 4);
        }
        acc = __builtin_amdgcn_mfma_f32_16x16x32_f16(av, bv, acc, 0, 0, 0);
    }

    const int jloc = n0 + quad * 4;       // row of reg 0 (within batch)
#pragma unroll
    for (int reg = 0; reg < 4; ++reg) {
        const float v  = acc[reg];
        const float vp = __shfl_xor(v, 1);     // partner o
        if ((col & 1) == 0) {
            h2 hv; hv.x = (_Float16)v; hv.y = (_Float16)vp;
            const int o2 = (o0 + col) >> 1;
            Wh16[(size_t)(b * Nq + jloc + reg) * 128 + o2] = hv;
            WhT16p[(size_t)b * 65536 + (size_t)o2 * 512 + jloc + reg] = hv;
        }
    }
    // j-pair layout: regs 0..3 are consecutive rows at fixed o -> two h2, one 8B store
    h4 jp;
    jp[0] = (_Float16)acc[0]; jp[1] = (_Float16)acc[1];
    jp[2] = (_Float16)acc[2]; jp[3] = (_Float16)acc[3];
    *(h4*)&WhTj16[(size_t)b * 65536 + (size_t)(o0 + col) * 256 + (jloc >> 1)] = jp;
}

// ---------------------------------------------------------------------------
// K23: fused e+softmax (phase A) and out = P @ Wh (phase B).
// Grid 1024 = (b, 2 i-rows), 512 threads -> 4 blocks/CU = 32 waves/CU (100%).
// Phase A: thread = j; FULL o-range per thread (no half-combine); per o2:
// pk_add + pk_max + dot2 (x2 rows) + r-dot2. NO max-pass (e bounded, exp
// safe in fp32; softmax shift-invariant). 3 barriers total.
// Phase B: thread = (row, o); dot2 over j-pairs from WhTj16; P fp16 in LDS.
// Uniforms (a16, Wh16 rows) stay global s_loads (R8: LDS-staging spills).
// ---------------------------------------------------------------------------
__global__ __launch_bounds__(512, 8) void k23(const h2* __restrict__ Wh16,
                                              const h2* __restrict__ WhT16p,
                                              const h2* __restrict__ WhTj16,
                                              const h2* __restrict__ a16,
                                              float* __restrict__ out) {
    const int t   = threadIdx.x;
    const int blk = blockIdx.x;           // 1024
    const int b   = blk & 3;
    const int i0  = (blk >> 2) << 1;      // 2 i-rows

    __shared__ float sR[512];             // r_j for all j of batch b
    __shared__ h2    sP16[2 * 256];       // normalized P, j-paired fp16
    __shared__ float wred[2][8];          // row sums per wave

    // ======================= Phase A: e + softmax -> sP16 ==================
    float p0, p1;                         // this thread's P values (rows 0,1)
    {
        const int j = t;                  // 0..511
        const h2* __restrict__ wjp = WhT16p + (size_t)b * 65536 + j;   // + o2*512
        const h2* __restrict__ wip = Wh16 + (size_t)(b * Nq + i0) * 128; // uniform

        float ab0 = 0.f, ab1 = 0.f, rja = 0.f;
        h2 cA[8], cB[8];

#define KA_L8(buf, ob)                                                      \
    _Pragma("unroll") for (int s = 0; s < 8; ++s)                           \
        buf[s] = wjp[((ob) + s) * 512];

#define KA_C8(buf, ob)                                                      \
    _Pragma("unroll") for (int s = 0; s < 8; ++s) {                         \
        const int o2 = (ob) + s;                                            \
        const h2 a2 = a16[o2];                                  /* s_load */\
        rja = fdot2f(a2, buf[s], rja);                                      \
        const h2 wi0 = wip[o2];                                 /* s_load */\
        const h2 wi1 = wip[128 + o2];                           /* s_load */\
        h2 w0 = buf[s] + wi0;                                   /* pk_add */\
        h2 x0 = __builtin_elementwise_max(w0, -w0);             /* pk_max */\
        ab0 = fdot2f(a2, x0, ab0);                              /* dot2   */\
        h2 w1 = buf[s] + wi1;                                               \
        h2 x1 = __builtin_elementwise_max(w1, -w1);                         \
        ab1 = fdot2f(a2, x1, ab1);                                          \
    }

        KA_L8(cA, 0)   KA_L8(cB, 8)
        KA_C8(cA, 0)   KA_L8(cA, 16)
        KA_C8(cB, 8)   KA_L8(cB, 24)
        KA_C8(cA, 16)  KA_L8(cA, 32)
        KA_C8(cB, 24)  KA_L8(cB, 40)
        KA_C8(cA, 32)  KA_L8(cA, 48)
        KA_C8(cB, 40)  KA_L8(cB, 56)
        KA_C8(cA, 48)  KA_L8(cA, 64)
        KA_C8(cB, 56)  KA_L8(cB, 72)
        KA_C8(cA, 64)  KA_L8(cA, 80)
        KA_C8(cB, 72)  KA_L8(cB, 88)
        KA_C8(cA, 80)  KA_L8(cA, 96)
        KA_C8(cB, 88)  KA_L8(cB, 104)
        KA_C8(cA, 96)  KA_L8(cA, 112)
        KA_C8(cB, 104) KA_L8(cB, 120)
        KA_C8(cA, 112)
        KA_C8(cB, 120)
#undef KA_L8
#undef KA_C8

        sR[j] = rja;                      // publish r_j
        __syncthreads();

        const float ri0 = sR[i0], ri1 = sR[i0 + 1];
        const float e0 = 0.6f * (ri0 + rja) + 0.4f * ab0;
        const float e1 = 0.6f * (ri1 + rja) + 0.4f * ab1;
        p0 = __expf(e0);                  // no max-sub: |e| <~ 13, safe
        p1 = __expf(e1);

        float s0 = p0, s1 = p1;
#pragma unroll
        for (int off = 32; off > 0; off >>= 1) {
            s0 += __shfl_xor(s0, off);
            s1 += __shfl_xor(s1, off);
        }
        const int lane = t & 63, wv = t >> 6;
        if (lane == 0) { wred[0][wv] = s0; wred[1][wv] = s1; }
        __syncthreads();

        const float4 q0a = *(const float4*)&wred[0][0];
        const float4 q0b = *(const float4*)&wred[0][4];
        const float4 q1a = *(const float4*)&wred[1][0];
        const float4 q1b = *(const float4*)&wred[1][4];
        const float inv0 = 1.0f / ((q0a.x + q0a.y + q0a.z + q0a.w) +
                                   (q0b.x + q0b.y + q0b.z + q0b.w));
        const float inv1 = 1.0f / ((q1a.x + q1a.y + q1a.z + q1a.w) +
                                   (q1b.x + q1b.y + q1b.z + q1b.w));
        const float q0 = p0 * inv0, q1 = p1 * inv1;
        const float q0p = __shfl_xor(q0, 1);   // partner j
        const float q1p = __shfl_xor(q1, 1);
        if ((j & 1) == 0) {
            h2 hv0; hv0.x = (_Float16)q0; hv0.y = (_Float16)q0p;
            h2 hv1; hv1.x = (_Float16)q1; hv1.y = (_Float16)q1p;
            sP16[j >> 1]       = hv0;
            sP16[256 + (j >> 1)] = hv1;
        }
        __syncthreads();
    }

    // ======================= Phase B: out = P @ Wh =========================
    {
        const int row = t >> 8;           // 0/1
        const int o   = t & 255;

        const h2* __restrict__ gW = WhTj16 + (size_t)b * 65536 + (size_t)o * 256; // + j2
        const h2* __restrict__ sPr = sP16 + row * 256;

        float acc = 0.f;
        h4 cA[8], cB[8];                  // each h4 = 2 j2 (4 j)

#define KB_L8(buf, jb)                                                      \
    _Pragma("unroll") for (int s = 0; s < 8; ++s)                           \
        buf[s] = *(const h4*)(gW + (jb) + 2 * s);

#define KB_C8(buf, jb)                                                      \
    _Pragma("unroll") for (int s = 0; s < 8; ++s) {                         \
        const h4 v = buf[s];                                                \
        const h4 pp = *(const h4*)(sPr + (jb) + 2 * s);   /* ds broadcast */\
        h2 lo; lo.x = v[0]; lo.y = v[1];                                    \
        h2 hi; hi.x = v[2]; hi.y = v[3];                                    \
        h2 plo; plo.x = pp[0]; plo.y = pp[1];                               \
        h2 phi; phi.x = pp[2]; phi.y = pp[3];                               \
        acc = fdot2f(plo, lo, acc);                                         \
        acc = fdot2f(phi, hi, acc);                                         \
    }

        KB_L8(cA, 0)   KB_L8(cB, 16)
        KB_C8(cA, 0)   KB_L8(cA, 32)
        KB_C8(cB, 16)  KB_L8(cB, 48)
        KB_C8(cA, 32)  KB_L8(cA, 64)
        KB_C8(cB, 48)  KB_L8(cB, 80)
        KB_C8(cA, 64)  KB_L8(cA, 96)
        KB_C8(cB, 80)  KB_L8(cB, 112)
        KB_C8(cA, 96)  KB_L8(cA, 128)
        KB_C8(cB, 112) KB_L8(cB, 144)
        KB_C8(cA, 128) KB_L8(cA, 160)
        KB_C8(cB, 144) KB_L8(cB, 176)
        KB_C8(cA, 160) KB_L8(cA, 192)
        KB_C8(cB, 176) KB_L8(cB, 208)
        KB_C8(cA, 192) KB_L8(cA, 224)
        KB_C8(cB, 208) KB_L8(cB, 240)
        KB_C8(cA, 224)
        KB_C8(cB, 240)
#undef KB_L8
#undef KB_C8

        out[(size_t)(b * Nq + i0 + row) * DOUT + o] = acc;   // coalesced
    }
}

// ---------------------------------------------------------------------------
extern "C" void kernel_launch(void* const* d_in, const int* in_sizes, int n_in,
                              void* d_out, int out_size, void* d_ws, size_t ws_size,
                              hipStream_t stream) {
    const float* H = (const float*)d_in[0];   // [4,512,512]
    const float* W = (const float*)d_in[1];   // [256,512]
    const float* a = (const float*)d_in[2];   // [256,1]
    float* out = (float*)d_out;               // [4,512,256]

    h2* Wh16   = (h2*)d_ws;                    // 262144 h2 (1 MB)  [n][o2]
    h2* WhT16p = Wh16 + 262144;                // 262144 h2 (1 MB)  [b][o2][j]
    h2* WhTj16 = WhT16p + 262144;              // 262144 h2 (1 MB)  [b][o][j2]
    h2* a16    = WhTj16 + 262144;              // 128 h2

    hipLaunchKernelGGL(k1_wh, dim3(512),  dim3(256), 0, stream, H, W, a,
                       Wh16, WhT16p, WhTj16, a16);
    hipLaunchKernelGGL(k23,   dim3(1024), dim3(512), 0, stream,
                       Wh16, WhT16p, WhTj16, a16, out);
}

// Round 15
// 153.564 us; speedup vs baseline: 1.0050x; 1.0050x over previous
//
#include <hip/hip_runtime.h>

// Problem constants (B=4, N=512, D_in=512, D_out=256), fp32 in/out.
constexpr int Bq   = 4;
constexpr int Nq   = 512;
constexpr int DIN  = 512;
constexpr int DOUT = 256;

typedef _Float16 h2  __attribute__((ext_vector_type(2)));
typedef _Float16 h4  __attribute__((ext_vector_type(4)));
typedef _Float16 h8  __attribute__((ext_vector_type(8)));
typedef float    f4v __attribute__((ext_vector_type(4)));

#if defined(__has_builtin) && __has_builtin(__builtin_amdgcn_fdot2)
__device__ __forceinline__ float fdot2f(h2 a, h2 b, float c) {
    return __builtin_amdgcn_fdot2(a, b, c, false);   // v_dot2_f32_f16
}
#else
__device__ __forceinline__ float fdot2f(h2 a, h2 b, float c) {
    return (float)a.x * (float)b.x + (float)a.y * (float)b.y + c;
}
#endif

// ---------------------------------------------------------------------------
// K1: Wh = H @ W^T via MFMA 16x16x32 f16, fp32->fp16 inline (R14, proven).
// Grid 512 x 256 thr. Wave = one 16x16 tile. A[m=lane&15][k=quad*8+j];
// C col=lane&15, row=quad*4+reg. Emits 3 fp16 layouts; block 0 converts a.
// ---------------------------------------------------------------------------
__global__ __launch_bounds__(256) void k1_wh(const float* __restrict__ H,
                                             const float* __restrict__ W,
                                             const float* __restrict__ a,
                                             h2* __restrict__ Wh16,
                                             h2* __restrict__ WhT16p,
                                             h2* __restrict__ WhTj16,
                                             h2* __restrict__ a16) {
    const int t    = threadIdx.x;
    const int w    = t >> 6;
    const int lane = t & 63;
    const int bid  = blockIdx.x;          // 512
    const int mt   = bid >> 2;            // 0..127
    const int b    = mt & 3;              // XCD spread
    const int n0   = (mt >> 2) << 4;      // 0..496
    const int o0   = ((bid & 3) << 6) + (w << 4);
    const int quad = lane >> 4;
    const int col  = lane & 15;

    if (bid == 0 && t < 128) {            // a -> fp16
        const float2 v = *(const float2*)&a[2 * t];
        h2 hv; hv.x = (_Float16)v.x; hv.y = (_Float16)v.y;
        a16[t] = hv;
    }

    const float* __restrict__ aPtr = H + (size_t)(b * Nq + n0 + col) * DIN + quad * 8;
    const float* __restrict__ bPtr = W + (size_t)(o0 + col) * DIN + quad * 8;

    f4v acc = {0.f, 0.f, 0.f, 0.f};
    float4 af0 = *(const float4*)aPtr;
    float4 af1 = *(const float4*)(aPtr + 4);
    float4 bf0 = *(const float4*)bPtr;
    float4 bf1 = *(const float4*)(bPtr + 4);

#pragma unroll
    for (int kb = 0; kb < 16; ++kb) {
        h8 av, bv;
        av[0] = (_Float16)af0.x; av[1] = (_Float16)af0.y;
        av[2] = (_Float16)af0.z; av[3] = (_Float16)af0.w;
        av[4] = (_Float16)af1.x; av[5] = (_Float16)af1.y;
        av[6] = (_Float16)af1.z; av[7] = (_Float16)af1.w;
        bv[0] = (_Float16)bf0.x; bv[1] = (_Float16)bf0.y;
        bv[2] = (_Float16)bf0.z; bv[3] = (_Float16)bf0.w;
        bv[4] = (_Float16)bf1.x; bv[5] = (_Float16)bf1.y;
        bv[6] = (_Float16)bf1.z; bv[7] = (_Float16)bf1.w;
        if (kb < 15) {
            af0 = *(const float4*)(aPtr + (kb + 1) * 32);
            af1 = *(const float4*)(aPtr + (kb + 1) * 32 + 4);
            bf0 = *(const float4*)(bPtr + (kb + 1) * 32);
            bf1 = *(const float4*)(bPtr + (kb + 1) * 32 + 4);
        }
        acc = __builtin_amdgcn_mfma_f32_16x16x32_f16(av, bv, acc, 0, 0, 0);
    }

    const int jloc = n0 + quad * 4;       // row of reg 0 (within batch)
#pragma unroll
    for (int reg = 0; reg < 4; ++reg) {
        const float v  = acc[reg];
        const float vp = __shfl_xor(v, 1);     // partner o
        if ((col & 1) == 0) {
            h2 hv; hv.x = (_Float16)v; hv.y = (_Float16)vp;
            const int o2 = (o0 + col) >> 1;
            Wh16[(size_t)(b * Nq + jloc + reg) * 128 + o2] = hv;
            WhT16p[(size_t)b * 65536 + (size_t)o2 * 512 + jloc + reg] = hv;
        }
    }
    h4 jp;
    jp[0] = (_Float16)acc[0]; jp[1] = (_Float16)acc[1];
    jp[2] = (_Float16)acc[2]; jp[3] = (_Float16)acc[3];
    *(h4*)&WhTj16[(size_t)b * 65536 + (size_t)(o0 + col) * 256 + (jloc >> 1)] = jp;
}

// ---------------------------------------------------------------------------
// K23: fused e+softmax + out = P @ Wh. Grid 512 = (b, 4 i-rows), 1024 thr.
// Phase A = R13's proven 41.8-µs shape: half h = t>>9 owns 64 o2, j = t&511,
// 4 rows -> 13 VALU per streamed dword (arithmetic intensity is the knob;
// R14's 2-row variant at 7 VALU/load ran 2.1x slower). NO max-pass (R14
// validated: e bounded, softmax shift-invariant). Phase B = R14's direct
// form: thread = (row = t>>8, o = t&255), dot2 over WhTj16, P fp16 in LDS,
// zero partial-reduce barriers. Uniforms stay global s_loads (R8 lesson).
// ---------------------------------------------------------------------------
__global__ __launch_bounds__(1024, 8) void k23(const h2* __restrict__ Wh16,
                                               const h2* __restrict__ WhT16p,
                                               const h2* __restrict__ WhTj16,
                                               const h2* __restrict__ a16,
                                               float* __restrict__ out) {
    const int t   = threadIdx.x;
    const int blk = blockIdx.x;           // 512
    const int b   = blk & 3;
    const int i0  = (blk >> 2) << 2;      // 4 i-rows

    __shared__ float sAb[4 * 512];        // 8 KB  (half-combine)
    __shared__ float sRh[512];            // 2 KB  (r half)
    __shared__ float sRf[512];            // 2 KB  (r final)
    __shared__ float wred[4][8];          // row sums per h0-wave
    __shared__ h2    sP16[4 * 256];       // 4 KB  (normalized P, j-paired)

    // ======================= Phase A: e + softmax -> sP16 ==================
    {
        const int h  = __builtin_amdgcn_readfirstlane(t >> 9);  // 0/1
        const int j  = t & 511;
        const int ob = h * 64;            // o2 base (64 o-pairs = 128 o)

        const h2* __restrict__ wjp = WhT16p + (size_t)b * 65536 + j;     // + o2*512
        const h2* __restrict__ wip = Wh16 + (size_t)(b * Nq + i0) * 128; // uniform

        float ab[4] = {0.f, 0.f, 0.f, 0.f};
        float rja = 0.f;
        h2 cA[8], cB[8];

#define KA_L8(buf, kb)                                                      \
    _Pragma("unroll") for (int s = 0; s < 8; ++s)                           \
        buf[s] = wjp[(ob + (kb) + s) * 512];

#define KA_C8(buf, kb)                                                      \
    _Pragma("unroll") for (int s = 0; s < 8; ++s) {                         \
        const int o2 = ob + (kb) + s;                                       \
        const h2 a2 = a16[o2];                                  /* s_load */\
        rja = fdot2f(a2, buf[s], rja);                                      \
        _Pragma("unroll") for (int rr = 0; rr < 4; ++rr) {                  \
            const h2 wi = wip[rr * 128 + o2];                   /* s_load */\
            h2 w  = buf[s] + wi;                                /* pk_add */\
            h2 aw = __builtin_elementwise_max(w, -w);           /* pk_max */\
            ab[rr] = fdot2f(a2, aw, ab[rr]);                    /* dot2   */\
        }                                                                   \
    }

        KA_L8(cA, 0)  KA_L8(cB, 8)
        KA_C8(cA, 0)  KA_L8(cA, 16)
        KA_C8(cB, 8)  KA_L8(cB, 24)
        KA_C8(cA, 16) KA_L8(cA, 32)
        KA_C8(cB, 24) KA_L8(cB, 40)
        KA_C8(cA, 32) KA_L8(cA, 48)
        KA_C8(cB, 40) KA_L8(cB, 56)
        KA_C8(cA, 48)
        KA_C8(cB, 56)
#undef KA_L8
#undef KA_C8

        // combine halves
        if (h == 1) {
#pragma unroll
            for (int rr = 0; rr < 4; ++rr) sAb[rr * 512 + j] = ab[rr];
            sRh[j] = rja;
        }
        __syncthreads();

        float rj = 0.f;
        if (h == 0) {
#pragma unroll
            for (int rr = 0; rr < 4; ++rr) ab[rr] += sAb[rr * 512 + j];
            rj = rja + sRh[j];
            sRf[j] = rj;
        }
        __syncthreads();                  // sRf visible

        float pv[4];
        if (h == 0) {
#pragma unroll
            for (int rr = 0; rr < 4; ++rr) {
                const float e = 0.6f * (sRf[i0 + rr] + rj) + 0.4f * ab[rr];
                pv[rr] = __expf(e);       // no max-sub: |e| bounded (~13)
            }
        }

        const int lane = t & 63;
        const int wv   = t >> 6;          // h0: waves 0..7
#pragma unroll
        for (int rr = 0; rr < 4; ++rr) {
            float v = (h == 0) ? pv[rr] : 0.f;
#pragma unroll
            for (int off = 32; off > 0; off >>= 1) v += __shfl_xor(v, off);
            if (lane == 0 && h == 0) wred[rr][wv] = v;
        }
        __syncthreads();

        if (h == 0) {
#pragma unroll
            for (int rr = 0; rr < 4; ++rr) {
                const float4 qa = *(const float4*)&wred[rr][0];
                const float4 qb = *(const float4*)&wred[rr][4];
                const float s = (qa.x + qa.y + qa.z + qa.w) +
                                (qb.x + qb.y + qb.z + qb.w);
                const float q  = pv[rr] * (1.0f / s);
                const float qp = __shfl_xor(q, 1);   // partner j
                if ((j & 1) == 0) {
                    h2 hv; hv.x = (_Float16)q; hv.y = (_Float16)qp;
                    sP16[rr * 256 + (j >> 1)] = hv;
                }
            }
        }
        __syncthreads();                  // sP16 ready
    }

    // ======================= Phase B: out = P @ Wh =========================
    {
        const int row = t >> 8;           // 0..3
        const int o   = t & 255;

        const h2* __restrict__ gW  = WhTj16 + (size_t)b * 65536 + (size_t)o * 256;
        const h2* __restrict__ sPr = sP16 + row * 256;

        float acc = 0.f;
        h4 cA[8], cB[8];                  // each h4 = 2 j2 (4 j)

#define KB_L8(buf, jb)                                                      \
    _Pragma("unroll") for (int s = 0; s < 8; ++s)                           \
        buf[s] = *(const h4*)(gW + (jb) + 2 * s);

#define KB_C8(buf, jb)                                                      \
    _Pragma("unroll") for (int s = 0; s < 8; ++s) {                         \
        const h4 v = buf[s];                                                \
        const h4 pp = *(const h4*)(sPr + (jb) + 2 * s);   /* ds broadcast */\
        h2 lo; lo.x = v[0]; lo.y = v[1];                                    \
        h2 hi; hi.x = v[2]; hi.y = v[3];                                    \
        h2 plo; plo.x = pp[0]; plo.y = pp[1];                               \
        h2 phi; phi.x = pp[2]; phi.y = pp[3];                               \
        acc = fdot2f(plo, lo, acc);                                         \
        acc = fdot2f(phi, hi, acc);                                         \
    }

        KB_L8(cA, 0)   KB_L8(cB, 16)
        KB_C8(cA, 0)   KB_L8(cA, 32)
        KB_C8(cB, 16)  KB_L8(cB, 48)
        KB_C8(cA, 32)  KB_L8(cA, 64)
        KB_C8(cB, 48)  KB_L8(cB, 80)
        KB_C8(cA, 64)  KB_L8(cA, 96)
        KB_C8(cB, 80)  KB_L8(cB, 112)
        KB_C8(cA, 96)  KB_L8(cA, 128)
        KB_C8(cB, 112) KB_L8(cB, 144)
        KB_C8(cA, 128) KB_L8(cA, 160)
        KB_C8(cB, 144) KB_L8(cB, 176)
        KB_C8(cA, 160) KB_L8(cA, 192)
        KB_C8(cB, 176) KB_L8(cB, 208)
        KB_C8(cA, 192) KB_L8(cA, 224)
        KB_C8(cB, 208) KB_L8(cB, 240)
        KB_C8(cA, 224)
        KB_C8(cB, 240)
#undef KB_L8
#undef KB_C8

        out[(size_t)(b * Nq + i0 + row) * DOUT + o] = acc;   // coalesced
    }
}

// ---------------------------------------------------------------------------
extern "C" void kernel_launch(void* const* d_in, const int* in_sizes, int n_in,
                              void* d_out, int out_size, void* d_ws, size_t ws_size,
                              hipStream_t stream) {
    const float* H = (const float*)d_in[0];   // [4,512,512]
    const float* W = (const float*)d_in[1];   // [256,512]
    const float* a = (const float*)d_in[2];   // [256,1]
    float* out = (float*)d_out;               // [4,512,256]

    h2* Wh16   = (h2*)d_ws;                    // 262144 h2 (1 MB)  [n][o2]
    h2* WhT16p = Wh16 + 262144;                // 262144 h2 (1 MB)  [b][o2][j]
    h2* WhTj16 = WhT16p + 262144;              // 262144 h2 (1 MB)  [b][o][j2]
    h2* a16    = WhTj16 + 262144;              // 128 h2

    hipLaunchKernelGGL(k1_wh, dim3(512), dim3(256),  0, stream, H, W, a,
                       Wh16, WhT16p, WhTj16, a16);
    hipLaunchKernelGGL(k23,   dim3(512), dim3(1024), 0, stream,
                       Wh16, WhT16p, WhTj16, a16, out);
}

// Round 16
// 113.215 us; speedup vs baseline: 1.3632x; 1.3564x over previous
//
#include <hip/hip_runtime.h>

// Problem constants (B=4, N=512, D_in=512, D_out=256), fp32 in/out.
constexpr int Bq   = 4;
constexpr int Nq   = 512;
constexpr int DIN  = 512;
constexpr int DOUT = 256;

typedef _Float16 h2  __attribute__((ext_vector_type(2)));
typedef _Float16 h8  __attribute__((ext_vector_type(8)));
typedef float    f4v __attribute__((ext_vector_type(4)));

#if defined(__has_builtin) && __has_builtin(__builtin_amdgcn_fdot2)
__device__ __forceinline__ float fdot2f(h2 a, h2 b, float c) {
    return __builtin_amdgcn_fdot2(a, b, c, false);   // v_dot2_f32_f16
}
#else
__device__ __forceinline__ float fdot2f(h2 a, h2 b, float c) {
    return (float)a.x * (float)b.x + (float)a.y * (float)b.y + c;
}
#endif

// ---------------------------------------------------------------------------
// K1: Wh = H @ W^T via MFMA 16x16x32 f16, fp32->fp16 inline. Grid 512 x 256.
// Wave = one 16x16 tile. A[m=lane&15][k=quad*8+j]; C col=lane&15,
// row=quad*4+reg. Emits 3 fp16 layouts:
//   Wh16[n][o2]        (phase-A uniform rows)
//   WhT16p[b][o2][j]   (phase-A j-stream: lane j consecutive -> coalesced)
//   WhTo16[b][j2][o]   (phase-B stream: lane o consecutive -> COALESCED;
//                       R14/R15's [o][j2] was a stride-512 gather = 2x k23)
// Block 0 converts a. No LDS, no barriers.
// ---------------------------------------------------------------------------
__global__ __launch_bounds__(256) void k1_wh(const float* __restrict__ H,
                                             const float* __restrict__ W,
                                             const float* __restrict__ a,
                                             h2* __restrict__ Wh16,
                                             h2* __restrict__ WhT16p,
                                             h2* __restrict__ WhTo16,
                                             h2* __restrict__ a16) {
    const int t    = threadIdx.x;
    const int w    = t >> 6;
    const int lane = t & 63;
    const int bid  = blockIdx.x;          // 512
    const int mt   = bid >> 2;            // 0..127
    const int b    = mt & 3;              // XCD spread
    const int n0   = (mt >> 2) << 4;      // 0..496
    const int o0   = ((bid & 3) << 6) + (w << 4);
    const int quad = lane >> 4;
    const int col  = lane & 15;

    if (bid == 0 && t < 128) {            // a -> fp16
        const float2 v = *(const float2*)&a[2 * t];
        h2 hv; hv.x = (_Float16)v.x; hv.y = (_Float16)v.y;
        a16[t] = hv;
    }

    const float* __restrict__ aPtr = H + (size_t)(b * Nq + n0 + col) * DIN + quad * 8;
    const float* __restrict__ bPtr = W + (size_t)(o0 + col) * DIN + quad * 8;

    f4v acc = {0.f, 0.f, 0.f, 0.f};
    float4 af0 = *(const float4*)aPtr;
    float4 af1 = *(const float4*)(aPtr + 4);
    float4 bf0 = *(const float4*)bPtr;
    float4 bf1 = *(const float4*)(bPtr + 4);

#pragma unroll
    for (int kb = 0; kb < 16; ++kb) {
        h8 av, bv;
        av[0] = (_Float16)af0.x; av[1] = (_Float16)af0.y;
        av[2] = (_Float16)af0.z; av[3] = (_Float16)af0.w;
        av[4] = (_Float16)af1.x; av[5] = (_Float16)af1.y;
        av[6] = (_Float16)af1.z; av[7] = (_Float16)af1.w;
        bv[0] = (_Float16)bf0.x; bv[1] = (_Float16)bf0.y;
        bv[2] = (_Float16)bf0.z; bv[3] = (_Float16)bf0.w;
        bv[4] = (_Float16)bf1.x; bv[5] = (_Float16)bf1.y;
        bv[6] = (_Float16)bf1.z; bv[7] = (_Float16)bf1.w;
        if (kb < 15) {
            af0 = *(const float4*)(aPtr + (kb + 1) * 32);
            af1 = *(const float4*)(aPtr + (kb + 1) * 32 + 4);
            bf0 = *(const float4*)(bPtr + (kb + 1) * 32);
            bf1 = *(const float4*)(bPtr + (kb + 1) * 32 + 4);
        }
        acc = __builtin_amdgcn_mfma_f32_16x16x32_f16(av, bv, acc, 0, 0, 0);
    }

    const int jloc = n0 + quad * 4;       // row of reg 0 (within batch)
#pragma unroll
    for (int reg = 0; reg < 4; ++reg) {
        const float v  = acc[reg];
        const float vp = __shfl_xor(v, 1);     // partner o
        if ((col & 1) == 0) {
            h2 hv; hv.x = (_Float16)v; hv.y = (_Float16)vp;
            const int o2 = (o0 + col) >> 1;
            Wh16[(size_t)(b * Nq + jloc + reg) * 128 + o2] = hv;
            WhT16p[(size_t)b * 65536 + (size_t)o2 * 512 + jloc + reg] = hv;
        }
    }
    // phase-B layout: [b][j2][o]; regs (0,1) and (2,3) are j-pairs at fixed o
    {
        h2 jp01; jp01.x = (_Float16)acc[0]; jp01.y = (_Float16)acc[1];
        h2 jp23; jp23.x = (_Float16)acc[2]; jp23.y = (_Float16)acc[3];
        const int j2 = jloc >> 1;
        WhTo16[(size_t)b * 65536 + (size_t)j2 * 256 + o0 + col]       = jp01;
        WhTo16[(size_t)b * 65536 + (size_t)(j2 + 1) * 256 + o0 + col] = jp23;
    }
}

// ---------------------------------------------------------------------------
// K23: fused e+softmax + out = P @ Wh. Grid 512 = (b, 4 i-rows), 1024 thr.
// Phase A: R13's proven 41.8-µs shape (half h owns 64 o2, j = t&511, 4 rows
// = 13 VALU per streamed dword), minus the max-pass (R14 validated).
// Phase B: thread = (row = t>>8, o = t&255); stream WhTo16[b][j2][o] --
// coalesced 256B/instr (lane o consecutive); P j-pairs broadcast from LDS;
// 1 dot2/load; no partial-reduce, coalesced fp32 store.
// Uniforms stay global s_loads (R8 lesson).
// ---------------------------------------------------------------------------
__global__ __launch_bounds__(1024, 8) void k23(const h2* __restrict__ Wh16,
                                               const h2* __restrict__ WhT16p,
                                               const h2* __restrict__ WhTo16,
                                               const h2* __restrict__ a16,
                                               float* __restrict__ out) {
    const int t   = threadIdx.x;
    const int blk = blockIdx.x;           // 512
    const int b   = blk & 3;
    const int i0  = (blk >> 2) << 2;      // 4 i-rows

    __shared__ float sAb[4 * 512];        // 8 KB  (half-combine)
    __shared__ float sRh[512];            // 2 KB  (r half)
    __shared__ float sRf[512];            // 2 KB  (r final)
    __shared__ float wred[4][8];          // row sums per h0-wave
    __shared__ h2    sP16[4 * 256];       // 4 KB  (normalized P, j-paired)

    // ======================= Phase A: e + softmax -> sP16 ==================
    {
        const int h  = __builtin_amdgcn_readfirstlane(t >> 9);  // 0/1
        const int j  = t & 511;
        const int ob = h * 64;            // o2 base (64 o-pairs = 128 o)

        const h2* __restrict__ wjp = WhT16p + (size_t)b * 65536 + j;     // + o2*512
        const h2* __restrict__ wip = Wh16 + (size_t)(b * Nq + i0) * 128; // uniform

        float ab[4] = {0.f, 0.f, 0.f, 0.f};
        float rja = 0.f;
        h2 cA[8], cB[8];

#define KA_L8(buf, kb)                                                      \
    _Pragma("unroll") for (int s = 0; s < 8; ++s)                           \
        buf[s] = wjp[(ob + (kb) + s) * 512];

#define KA_C8(buf, kb)                                                      \
    _Pragma("unroll") for (int s = 0; s < 8; ++s) {                         \
        const int o2 = ob + (kb) + s;                                       \
        const h2 a2 = a16[o2];                                  /* s_load */\
        rja = fdot2f(a2, buf[s], rja);                                      \
        _Pragma("unroll") for (int rr = 0; rr < 4; ++rr) {                  \
            const h2 wi = wip[rr * 128 + o2];                   /* s_load */\
            h2 w  = buf[s] + wi;                                /* pk_add */\
            h2 aw = __builtin_elementwise_max(w, -w);           /* pk_max */\
            ab[rr] = fdot2f(a2, aw, ab[rr]);                    /* dot2   */\
        }                                                                   \
    }

        KA_L8(cA, 0)  KA_L8(cB, 8)
        KA_C8(cA, 0)  KA_L8(cA, 16)
        KA_C8(cB, 8)  KA_L8(cB, 24)
        KA_C8(cA, 16) KA_L8(cA, 32)
        KA_C8(cB, 24) KA_L8(cB, 40)
        KA_C8(cA, 32) KA_L8(cA, 48)
        KA_C8(cB, 40) KA_L8(cB, 56)
        KA_C8(cA, 48)
        KA_C8(cB, 56)
#undef KA_L8
#undef KA_C8

        // combine halves
        if (h == 1) {
#pragma unroll
            for (int rr = 0; rr < 4; ++rr) sAb[rr * 512 + j] = ab[rr];
            sRh[j] = rja;
        }
        __syncthreads();

        float rj = 0.f;
        if (h == 0) {
#pragma unroll
            for (int rr = 0; rr < 4; ++rr) ab[rr] += sAb[rr * 512 + j];
            rj = rja + sRh[j];
            sRf[j] = rj;
        }
        __syncthreads();                  // sRf visible

        float pv[4];
        if (h == 0) {
#pragma unroll
            for (int rr = 0; rr < 4; ++rr) {
                const float e = 0.6f * (sRf[i0 + rr] + rj) + 0.4f * ab[rr];
                pv[rr] = __expf(e);       // no max-sub: |e| bounded (~13)
            }
        }

        const int lane = t & 63;
        const int wv   = t >> 6;          // h0: waves 0..7
#pragma unroll
        for (int rr = 0; rr < 4; ++rr) {
            float v = (h == 0) ? pv[rr] : 0.f;
#pragma unroll
            for (int off = 32; off > 0; off >>= 1) v += __shfl_xor(v, off);
            if (lane == 0 && h == 0) wred[rr][wv] = v;
        }
        __syncthreads();

        if (h == 0) {
#pragma unroll
            for (int rr = 0; rr < 4; ++rr) {
                const float4 qa = *(const float4*)&wred[rr][0];
                const float4 qb = *(const float4*)&wred[rr][4];
                const float s = (qa.x + qa.y + qa.z + qa.w) +
                                (qb.x + qb.y + qb.z + qb.w);
                const float q  = pv[rr] * (1.0f / s);
                const float qp = __shfl_xor(q, 1);   // partner j
                if ((j & 1) == 0) {
                    h2 hv; hv.x = (_Float16)q; hv.y = (_Float16)qp;
                    sP16[rr * 256 + (j >> 1)] = hv;
                }
            }
        }
        __syncthreads();                  // sP16 ready
    }

    // ======================= Phase B: out = P @ Wh =========================
    {
        const int row = t >> 8;           // 0..3
        const int o   = t & 255;

        const h2* __restrict__ gW  = WhTo16 + (size_t)b * 65536 + o;  // + j2*256
        const h2* __restrict__ sPr = sP16 + row * 256;

        float acc = 0.f;
        h2 cA[16], cB[16];

#define KB_L16(buf, jb)                                                     \
    _Pragma("unroll") for (int s = 0; s < 16; ++s)                          \
        buf[s] = gW[((jb) + s) * 256];

#define KB_C16(buf, jb)                                                     \
    _Pragma("unroll") for (int s = 0; s < 16; ++s)                          \
        acc = fdot2f(sPr[(jb) + s], buf[s], acc);      /* ds bcast + dot2 */

        KB_L16(cA, 0)    KB_L16(cB, 16)
        KB_C16(cA, 0)    KB_L16(cA, 32)
        KB_C16(cB, 16)   KB_L16(cB, 48)
        KB_C16(cA, 32)   KB_L16(cA, 64)
        KB_C16(cB, 48)   KB_L16(cB, 80)
        KB_C16(cA, 64)   KB_L16(cA, 96)
        KB_C16(cB, 80)   KB_L16(cB, 112)
        KB_C16(cA, 96)   KB_L16(cA, 128)
        KB_C16(cB, 112)  KB_L16(cB, 144)
        KB_C16(cA, 128)  KB_L16(cA, 160)
        KB_C16(cB, 144)  KB_L16(cB, 176)
        KB_C16(cA, 160)  KB_L16(cA, 192)
        KB_C16(cB, 176)  KB_L16(cB, 208)
        KB_C16(cA, 192)  KB_L16(cA, 224)
        KB_C16(cB, 208)  KB_L16(cB, 240)
        KB_C16(cA, 224)
        KB_C16(cB, 240)
#undef KB_L16
#undef KB_C16

        out[(size_t)(b * Nq + i0 + row) * DOUT + o] = acc;   // coalesced
    }
}

// ---------------------------------------------------------------------------
extern "C" void kernel_launch(void* const* d_in, const int* in_sizes, int n_in,
                              void* d_out, int out_size, void* d_ws, size_t ws_size,
                              hipStream_t stream) {
    const float* H = (const float*)d_in[0];   // [4,512,512]
    const float* W = (const float*)d_in[1];   // [256,512]
    const float* a = (const float*)d_in[2];   // [256,1]
    float* out = (float*)d_out;               // [4,512,256]

    h2* Wh16   = (h2*)d_ws;                    // 262144 h2 (1 MB)  [n][o2]
    h2* WhT16p = Wh16 + 262144;                // 262144 h2 (1 MB)  [b][o2][j]
    h2* WhTo16 = WhT16p + 262144;              // 262144 h2 (1 MB)  [b][j2][o]
    h2* a16    = WhTo16 + 262144;              // 128 h2

    hipLaunchKernelGGL(k1_wh, dim3(512), dim3(256),  0, stream, H, W, a,
                       Wh16, WhT16p, WhTo16, a16);
    hipLaunchKernelGGL(k23,   dim3(512), dim3(1024), 0, stream,
                       Wh16, WhT16p, WhTo16, a16, out);
}